// Round 5
// baseline (237.436 us; speedup 1.0000x reference)
//
#include <hip/hip_runtime.h>
#include <hip/hip_bf16.h>
#include <math.h>

// Problem constants
constexpr int NBv = 4;      // num blocks
constexpr int Dv  = 128;    // hidden dim
constexpr int NSv = 16;     // state dim
constexpr int Bv  = 4;      // batch
constexpr int Lv  = 4096;   // seq len
constexpr int Tv  = Bv * Lv;        // 16384 tokens
constexpr int INv = 32;
constexpr int OUTv = 32;
constexpr int CLv = 64;             // chunk length
constexpr int CHv = Lv / CLv;       // 64 chunks
constexpr int Wv  = 32;             // scan warm-up steps

typedef __attribute__((ext_vector_type(8))) short bf8v;   // 8 bf16 (4 VGPR)
typedef __attribute__((ext_vector_type(4))) float f4v;

__device__ __forceinline__ float softplus_f(float x) {
    return (x > 20.f) ? x : log1pf(__expf(x));
}
__device__ __forceinline__ float gelu_f(float x) {
    return 0.5f * x * (1.f + erff(x * 0.70710678118654752f));
}
__device__ __forceinline__ unsigned short f2bf(float x) {   // RNE f32->bf16
    union { float f; unsigned u; } v; v.f = x;
    unsigned r = v.u + 0x7FFFu + ((v.u >> 16) & 1u);
    return (unsigned short)(r >> 16);
}
__device__ __forceinline__ float bf2f(unsigned short u) {
    union { unsigned u; float f; } v; v.u = (unsigned)u << 16; return v.f;
}
__device__ __forceinline__ bf8v pack8(const float* s) {
    bf8v r;
#pragma unroll
    for (int i = 0; i < 8; ++i) r[i] = (short)f2bf(s[i]);
    return r;
}

// DPP row-rotate (within 16-lane rows) — pure VALU cross-lane.
template<int CTRL>
__device__ __forceinline__ float dpp_ror(float x) {
    return __int_as_float(__builtin_amdgcn_mov_dpp(__float_as_int(x), CTRL, 0xf, 0xf, true));
}
__device__ __forceinline__ float row16_sum(float t) {
    t += dpp_ror<0x121>(t);
    t += dpp_ror<0x122>(t);
    t += dpp_ror<0x124>(t);
    t += dpp_ror<0x128>(t);
    return t;
}

// ---------------- prep: transpose+convert weights to bf16 ----------------
__global__ __launch_bounds__(256) void prep_kernel(const float* __restrict__ Wdt,
                                                   const float* __restrict__ WB,
                                                   const float* __restrict__ WC,
                                                   const float* __restrict__ glu_w,
                                                   unsigned short* __restrict__ wcombB,
                                                   unsigned short* __restrict__ gluTB) {
    __shared__ float tl[64][65];
    int bid = blockIdx.x;
    int blk = bid >> 4, t = bid & 15;
    const float* src; unsigned short* dst;
    int sR0, sC0, C, stride, orow0;
    if (t < 4) {
        src = Wdt + (size_t)blk * 128 * 128; stride = 128;
        sR0 = (t >> 1) * 64; sC0 = (t & 1) * 64; C = 64;
        dst = wcombB + (size_t)blk * 160 * 128; orow0 = sC0;
    } else if (t < 6) {
        src = WB + (size_t)blk * 128 * 16; stride = 16;
        sR0 = (t - 4) * 64; sC0 = 0; C = 16;
        dst = wcombB + (size_t)blk * 160 * 128; orow0 = 128;
    } else if (t < 8) {
        src = WC + (size_t)blk * 128 * 16; stride = 16;
        sR0 = (t - 6) * 64; sC0 = 0; C = 16;
        dst = wcombB + (size_t)blk * 160 * 128; orow0 = 144;
    } else {
        int g = t - 8;
        src = glu_w + (size_t)blk * 128 * 256; stride = 256;
        sR0 = (g >> 2) * 64; sC0 = (g & 3) * 64; C = 64;
        dst = gluTB + (size_t)blk * 256 * 128; orow0 = sC0;
    }
    int tid = threadIdx.x;
    int elems = 64 * C;
    for (int idx = tid; idx < elems; idx += 256) {
        int r = (C == 64) ? (idx >> 6) : (idx >> 4);
        int c = idx & (C - 1);
        tl[r][c] = src[(size_t)(sR0 + r) * stride + sC0 + c];
    }
    __syncthreads();
    for (int idx = tid; idx < elems; idx += 256) {
        int c = idx >> 6, r = idx & 63;
        dst[(size_t)(orow0 + c) * 128 + sR0 + r] = f2bf(tl[r][c]);
    }
}

// ---------------- encoder ----------------
__global__ __launch_bounds__(256) void enc_kernel(const float* __restrict__ x,
                                                  const float* __restrict__ w,
                                                  const float* __restrict__ b,
                                                  float* __restrict__ h) {
    int idx = blockIdx.x * 256 + threadIdx.x;
    int d = idx & (Dv - 1);
    int t = idx >> 7;
    const float* xr = x + (size_t)t * INv;
    float acc = b[d];
#pragma unroll
    for (int k = 0; k < INv; ++k) acc = fmaf(xr[k], w[k * Dv + d], acc);
    h[idx] = acc;
}

// ---------------- fused block: LN + proj-MFMA + scan + GELU + GLU + residual ----
// grid: B*CH = 256 WGs, 512 threads (8 waves). WG = one 64-token chunk + 32 warm-up.
__global__ __launch_bounds__(512, 2) void fused_block(const float* __restrict__ h_in,
                                                      const float* __restrict__ nw,
                                                      const float* __restrict__ nb,
                                                      const unsigned short* __restrict__ wcomb,
                                                      const float* __restrict__ bdt,
                                                      const float* __restrict__ A_log,
                                                      const float* __restrict__ Dp,
                                                      const unsigned short* __restrict__ gluT,
                                                      const float* __restrict__ gb,
                                                      float* __restrict__ h_out) {
    // LDS regions (112896 B total):
    //  uA   @0      : bf16 u  [96 rows][16 chunks of 8] swizzled        24576 B
    //  W    @24576  : phase B: wB [160][16] (40960) -> dldlu u32[128][100] (51200)
    //                 -> phase D: gwS [256][16] (65536)                 65536 B
    //  bmS  @90112  : bf16 [16][100]                                     3200 B
    //  cmS  @93312  : bf16 [16][100]                                     3200 B
    //  zA   @96512  : bf16 z [64 rows][16 chunks] swizzled              16384 B
    __shared__ __align__(16) char smem[112896];
    bf8v* uA = (bf8v*)smem;
    char* Wreg = smem + 24576;
    bf8v* wB = (bf8v*)Wreg;
    unsigned int* dldlu = (unsigned int*)Wreg;
    bf8v* gwS = (bf8v*)Wreg;
    unsigned short* bmS = (unsigned short*)(smem + 90112);
    unsigned short* cmS = (unsigned short*)(smem + 93312);
    bf8v* zA = (bf8v*)(smem + 96512);

    int tid = threadIdx.x;
    int chunk = blockIdx.x;
    int b = chunk >> 6, c = chunk & 63;
    int t0 = b * Lv + c * CLv;     // first output token
    int tstart = t0 - Wv;          // first staged token

    // ---- Phase A: stage proj weights + LN 96 tokens -> uA (bf16) ----
    {
        const bf8v* gwc = (const bf8v*)wcomb;
#pragma unroll
        for (int j = 0; j < 5; ++j) {
            int idx = tid + j * 512;           // 2560 chunks
            int row = idx >> 4, cc = idx & 15;
            wB[(row << 4) | (cc ^ (row & 7))] = gwc[idx];
        }
        if (tid < 384) {
            int l = tid >> 2, q = tid & 3;     // staged row l, quarter q (32 dims)
            bool valid = (c != 0) || (l >= Wv);
            float g = valid ? 1.f : 0.f;
            float hv[32];
            if (valid) {
                const float* hr = h_in + (size_t)(tstart + l) * Dv + q * 32;
#pragma unroll
                for (int j = 0; j < 8; ++j) *(f4v*)&hv[j * 4] = *(const f4v*)&hr[j * 4];
            } else {
#pragma unroll
                for (int j = 0; j < 32; ++j) hv[j] = 0.f;
            }
            float s1 = 0.f, s2 = 0.f;
#pragma unroll
            for (int m = 0; m < 32; ++m) { s1 += hv[m]; s2 += hv[m] * hv[m]; }
            s1 += __shfl_xor(s1, 1); s2 += __shfl_xor(s2, 1);
            s1 += __shfl_xor(s1, 2); s2 += __shfl_xor(s2, 2);
            float mu = s1 * (1.f / 128.f);
            float var = s2 * (1.f / 128.f) - mu * mu;
            float rs = rsqrtf(var + 1e-5f);
#pragma unroll
            for (int jj = 0; jj < 4; ++jj) {
                float uv[8];
#pragma unroll
                for (int e = 0; e < 8; ++e) {
                    int m = jj * 8 + e;
                    uv[e] = ((hv[m] - mu) * rs * nw[q * 32 + m] + nb[q * 32 + m]) * g;
                }
                uA[(l << 4) | ((4 * q + jj) ^ (l & 7))] = pack8(uv);
            }
        }
    }
    __syncthreads();

    int lane = tid & 63, w = tid >> 6;
    int lr = lane & 15, lg = lane >> 4;

    // ---- Phase B: proj MFMA, M=96 x N=160 x K=128; 60 tiles strided over 8 waves ----
    f4v acc[8];
    f4v zero = {0.f, 0.f, 0.f, 0.f};
#pragma unroll
    for (int j8 = 0; j8 < 8; ++j8) acc[j8] = zero;
#pragma unroll
    for (int j8 = 0; j8 < 8; ++j8) {
        int idx = w + 8 * j8;
        if (idx < 60) {
            int mt = idx % 6, nt = idx / 6;
            int arow = mt * 16 + lr, brow = nt * 16 + lr;
#pragma unroll
            for (int ks = 0; ks < 4; ++ks) {
                bf8v a = uA[(arow << 4) | ((4 * ks + lg) ^ (arow & 7))];
                bf8v bb = wB[(brow << 4) | ((4 * ks + lg) ^ (brow & 7))];
                acc[j8] = __builtin_amdgcn_mfma_f32_16x16x32_bf16(a, bb, acc[j8], 0, 0, 0);
            }
        }
    }
    __syncthreads();   // wB dead; region becomes dldlu

    // ---- Phase B epilogue: softplus -> pack (dl|dlu) bf16 pairs; Bm/Cm -> bf16 ----
#pragma unroll
    for (int j8 = 0; j8 < 8; ++j8) {
        int idx = w + 8 * j8;
        if (idx < 60) {
            int mt = idx % 6, nt = idx / 6;
            int ncol = nt * 16 + lr;
            int l0 = mt * 16 + 4 * lg;
            if (nt < 8) {
                int d = ncol;
                float bb = bdt[d];
                unsigned pk[4];
#pragma unroll
                for (int r = 0; r < 4; ++r) {
                    int l = l0 + r;
                    float dlv = softplus_f(acc[j8][r] + bb);
                    int cc = (d >> 3) ^ (l & 7);
                    unsigned short us = ((const unsigned short*)uA)[((l << 4) | cc) * 8 + (d & 7)];
                    float dlu = dlv * bf2f(us);
                    pk[r] = ((unsigned)f2bf(dlv) << 16) | (unsigned)f2bf(dlu);
                }
                *(uint4*)&dldlu[d * 100 + l0] = make_uint4(pk[0], pk[1], pk[2], pk[3]);
            } else if (nt == 8) {
                int n = lr;
                uint2 p;
                p.x = (unsigned)f2bf(acc[j8][0]) | ((unsigned)f2bf(acc[j8][1]) << 16);
                p.y = (unsigned)f2bf(acc[j8][2]) | ((unsigned)f2bf(acc[j8][3]) << 16);
                *(uint2*)&bmS[n * 100 + l0] = p;
            } else {
                int n = lr;
                uint2 p;
                p.x = (unsigned)f2bf(acc[j8][0]) | ((unsigned)f2bf(acc[j8][1]) << 16);
                p.y = (unsigned)f2bf(acc[j8][2]) | ((unsigned)f2bf(acc[j8][3]) << 16);
                *(uint2*)&cmS[n * 100 + l0] = p;
            }
        }
    }
    __syncthreads();

    // ---- Phase C: scan. wave w owns d in [16w,16w+16); thread = (lg, n); 4 chains ----
    {
        int n = lr;
        float A2[4], hh[4];
#pragma unroll
        for (int cch = 0; cch < 4; ++cch) {
            int d = 16 * w + 4 * cch + lg;
            A2[cch] = -__expf(A_log[d * NSv + n]) * 1.4426950408889634f;
            hh[cch] = 0.f;
        }
        // warm-up
#pragma unroll 2
        for (int l4 = 0; l4 < Wv; l4 += 4) {
            uint2 bmp = *(const uint2*)&bmS[n * 100 + l4];
            float bmf[4] = {__uint_as_float(bmp.x << 16), __uint_as_float(bmp.x & 0xFFFF0000u),
                            __uint_as_float(bmp.y << 16), __uint_as_float(bmp.y & 0xFFFF0000u)};
#pragma unroll
            for (int cch = 0; cch < 4; ++cch) {
                int d = 16 * w + 4 * cch + lg;
                uint4 pk4 = *(const uint4*)&dldlu[d * 100 + l4];
                unsigned pks[4] = {pk4.x, pk4.y, pk4.z, pk4.w};
#pragma unroll
                for (int k = 0; k < 4; ++k) {
                    float dl = __uint_as_float(pks[k] & 0xFFFF0000u);
                    float dlu = __uint_as_float(pks[k] << 16);
                    float dA = __builtin_amdgcn_exp2f(dl * A2[cch]);
                    hh[cch] = fmaf(dA, hh[cch], dlu * bmf[k]);
                }
            }
        }
        // main: recurrence + y reduce + scattered zA write (lanes n<4 cover 4 steps)
#pragma unroll 2
        for (int l4 = Wv; l4 < Wv + CLv; l4 += 4) {
            uint2 bmp = *(const uint2*)&bmS[n * 100 + l4];
            uint2 cmp = *(const uint2*)&cmS[n * 100 + l4];
            float bmf[4] = {__uint_as_float(bmp.x << 16), __uint_as_float(bmp.x & 0xFFFF0000u),
                            __uint_as_float(bmp.y << 16), __uint_as_float(bmp.y & 0xFFFF0000u)};
            float cmf[4] = {__uint_as_float(cmp.x << 16), __uint_as_float(cmp.x & 0xFFFF0000u),
                            __uint_as_float(cmp.y << 16), __uint_as_float(cmp.y & 0xFFFF0000u)};
#pragma unroll
            for (int cch = 0; cch < 4; ++cch) {
                int d = 16 * w + 4 * cch + lg;
                uint4 pk4 = *(const uint4*)&dldlu[d * 100 + l4];
                unsigned pks[4] = {pk4.x, pk4.y, pk4.z, pk4.w};
                float yk[4];
#pragma unroll
                for (int k = 0; k < 4; ++k) {
                    float dl = __uint_as_float(pks[k] & 0xFFFF0000u);
                    float dlu = __uint_as_float(pks[k] << 16);
                    float dA = __builtin_amdgcn_exp2f(dl * A2[cch]);
                    hh[cch] = fmaf(dA, hh[cch], dlu * bmf[k]);
                    yk[k] = row16_sum(hh[cch] * cmf[k]);
                }
                if (n < 4) {
                    float yv = (n == 0) ? yk[0] : (n == 1) ? yk[1] : (n == 2) ? yk[2] : yk[3];
                    int lrow = l4 - Wv + n;
                    int cc = (d >> 3) ^ (lrow & 7);
                    ((unsigned short*)zA)[((lrow << 4) | cc) * 8 + (d & 7)] = f2bf(yv);
                }
            }
        }
    }
    __syncthreads();   // dldlu dead; region becomes gwS

    // ---- Phase C2: stage GLU weights + in-place gelu(y + Dp*u) on zA ----
    {
        const bf8v* gg = (const bf8v*)gluT;
#pragma unroll
        for (int j = 0; j < 8; ++j) {
            int idx = tid + j * 512;           // 4096 chunks
            int row = idx >> 4, cc = idx & 15;
            gwS[(row << 4) | (cc ^ (row & 7))] = gg[idx];
        }
        int row = tid >> 3;                    // 0..63
        int ccb = (tid & 7) * 2;
#pragma unroll
        for (int jj = 0; jj < 2; ++jj) {
            int cc = ccb + jj;
            int sw = (row << 4) | (cc ^ (row & 7));
            bf8v yv8 = zA[sw];
            bf8v uv8 = uA[((row + 32) << 4) | (cc ^ (row & 7))];
            f4v dpa = *(const f4v*)&Dp[cc * 8];
            f4v dpb = *(const f4v*)&Dp[cc * 8 + 4];
            bf8v o;
#pragma unroll
            for (int e = 0; e < 8; ++e) {
                float y = bf2f((unsigned short)yv8[e]);
                float uu = bf2f((unsigned short)uv8[e]);
                float dpv = (e < 4) ? dpa[e] : dpb[e - 4];
                o[e] = (short)f2bf(gelu_f(fmaf(dpv, uu, y)));
            }
            zA[sw] = o;
        }
    }
    __syncthreads();

    // ---- Phase D: GLU MFMA, M=64 x N=256 x K=128; wave w -> val col-tile w, gate w+8 ----
    {
        f4v accV[4], accG[4];
#pragma unroll
        for (int mt = 0; mt < 4; ++mt) { accV[mt] = zero; accG[mt] = zero; }
        bf8v bv[4], bg[4];
        int rv = w * 16 + lr, rg = rv + 128;
#pragma unroll
        for (int ks = 0; ks < 4; ++ks) {
            bv[ks] = gwS[(rv << 4) | ((4 * ks + lg) ^ (rv & 7))];
            bg[ks] = gwS[(rg << 4) | ((4 * ks + lg) ^ (rg & 7))];
        }
#pragma unroll
        for (int mt = 0; mt < 4; ++mt) {
            int arow = mt * 16 + lr;
#pragma unroll
            for (int ks = 0; ks < 4; ++ks) {
                bf8v a = zA[(arow << 4) | ((4 * ks + lg) ^ (arow & 7))];
                accV[mt] = __builtin_amdgcn_mfma_f32_16x16x32_bf16(a, bv[ks], accV[mt], 0, 0, 0);
                accG[mt] = __builtin_amdgcn_mfma_f32_16x16x32_bf16(a, bg[ks], accG[mt], 0, 0, 0);
            }
        }
        float gbv = gb[rv], gbg = gb[128 + rv];
#pragma unroll
        for (int mt = 0; mt < 4; ++mt) {
#pragma unroll
            for (int r = 0; r < 4; ++r) {
                int t = t0 + mt * 16 + 4 * lg + r;
                float val = accV[mt][r] + gbv;
                float gate = accG[mt][r] + gbg;
                float sig = 1.f / (1.f + __expf(-gate));
                size_t off = (size_t)t * Dv + rv;
                h_out[off] = fmaf(val, sig, h_in[off]);
            }
        }
    }
}

// ---------------- decoder ----------------
__global__ __launch_bounds__(256) void dec_kernel(const float* __restrict__ h,
                                                  const float* __restrict__ w,
                                                  const float* __restrict__ b,
                                                  float* __restrict__ out) {
    int idx = blockIdx.x * 256 + threadIdx.x;
    int o = idx & (OUTv - 1);
    int t = idx >> 5;
    const float* hr = h + (size_t)t * Dv;
    float acc = b[o];
#pragma unroll 8
    for (int d = 0; d < Dv; ++d) acc = fmaf(hr[d], w[d * OUTv + o], acc);
    out[idx] = tanhf(acc);
}

extern "C" void kernel_launch(void* const* d_in, const int* in_sizes, int n_in,
                              void* d_out, int out_size, void* d_ws, size_t ws_size,
                              hipStream_t stream) {
    (void)in_sizes; (void)n_in; (void)out_size; (void)ws_size;
    const float* x     = (const float*)d_in[0];
    const float* enc_w = (const float*)d_in[1];
    const float* enc_b = (const float*)d_in[2];
    const float* norm_w= (const float*)d_in[3];
    const float* norm_b= (const float*)d_in[4];
    const float* A_log = (const float*)d_in[5];
    const float* Dp    = (const float*)d_in[6];
    const float* Wdt   = (const float*)d_in[7];
    const float* bdt   = (const float*)d_in[8];
    const float* WB    = (const float*)d_in[9];
    const float* WC    = (const float*)d_in[10];
    const float* glu_w = (const float*)d_in[11];
    const float* glu_b = (const float*)d_in[12];
    const float* dec_w = (const float*)d_in[13];
    const float* dec_b = (const float*)d_in[14];
    float* out = (float*)d_out;
    float* ws = (float*)d_ws;

    float* h0 = ws;
    float* h1 = h0 + (size_t)Tv * Dv;
    unsigned short* wcombB = (unsigned short*)(h1 + (size_t)Tv * Dv);
    unsigned short* gluTB  = wcombB + (size_t)NBv * 160 * 128;

    prep_kernel<<<NBv * 16, 256, 0, stream>>>(Wdt, WB, WC, glu_w, wcombB, gluTB);
    enc_kernel<<<Tv * Dv / 256, 256, 0, stream>>>(x, enc_w, enc_b, h0);
    float* hin = h0;
    float* hout = h1;
    for (int i = 0; i < NBv; ++i) {
        fused_block<<<Bv * CHv, 512, 0, stream>>>(hin,
            norm_w + i * Dv, norm_b + i * Dv,
            wcombB + (size_t)i * 160 * 128, bdt + i * Dv,
            A_log + (size_t)i * Dv * NSv, Dp + i * Dv,
            gluTB + (size_t)i * 256 * 128, glu_b + (size_t)i * 2 * Dv,
            hout);
        float* tmp = hin; hin = hout; hout = tmp;
    }
    dec_kernel<<<Tv * OUTv / 256, 256, 0, stream>>>(hin, dec_w, dec_b, out);
}